// Round 9
// baseline (277.635 us; speedup 1.0000x reference)
//
#include <hip/hip_runtime.h>
#include <stdint.h>

#define BB 32
#define LL 512
#define NNODES 1024
#define DD 64
#define TOPK 20
#define NTOT (BB*NNODES)     // 32768
#define LNSZ (LL*NNODES)     // 524288

typedef short short8 __attribute__((ext_vector_type(8)));
typedef float floatx4 __attribute__((ext_vector_type(4)));

__device__ __forceinline__ float bf2f(unsigned short u){
    union { unsigned int i; float f; } x; x.i = ((unsigned int)u) << 16; return x.f;
}
__device__ __forceinline__ unsigned short f2bf(float f){
    union { float f; unsigned int i; } x; x.f = f;
    unsigned int u = x.i;
    return (unsigned short)((u + 0x7FFFu + ((u >> 16) & 1u)) >> 16);
}
__device__ __forceinline__ void unpack2(unsigned int w, float& lo, float& hi){
    union { unsigned int i; float f; } a, b;
    a.i = w << 16; b.i = w & 0xFFFF0000u;
    lo = a.f; hi = b.f;
}
__device__ __forceinline__ float ldf(const void* p, int i, int isf){
    return isf ? ((const float*)p)[i] : bf2f(((const unsigned short*)p)[i]);
}
// Inline per-wave dtype detection (1 = fp32). Same crazy-test as the old kd kernel;
// 64 fixed sample addresses -> L2-resident after first wave; deterministic per wave.
__device__ __forceinline__ int detect_isf(const void* xv){
    const unsigned short* x = (const unsigned short*)xv;
    int lane = threadIdx.x & 63;
    unsigned int idx = ((unsigned)lane * 131071u) & 0x7FFFFFu;
    float v = bf2f(x[idx * 2]);
    float a = fabsf(v);
    int crazy = (!(a <= 1e3f)) || (v != 0.f && a < 1e-6f);
    unsigned long long m = __ballot(crazy);
    return __popcll(m) > 16;
}

// K01: k1a partial sums (all 512 blocks) + prep duties (blocks < 128):
//   Wt transpose, embT (64x1024 fp32), rsqm (exact sq-tree), eai/eaj, stats zero (block 0).
__global__ void __launch_bounds__(256) k01_prep(const void* x, const void* lw, unsigned short* wt,
                                                const void* emb, const void* aemi, const void* aemj,
                                                float* eai, float* eaj, float* embT, float* rsqm,
                                                float* part, float* stats){
    int isf = detect_isf(x);
    int t = threadIdx.x;
    if (blockIdx.x == 0) stats[t] = 0.f;
    if (blockIdx.x < 128){
        int id = blockIdx.x * 256 + t;                // 0..32767
        int k = id >> 6, d = id & 63;
        unsigned short w = isf ? f2bf(((const float*)lw)[id]) : ((const unsigned short*)lw)[id];
        wt[d * 512 + k] = w;
        {
            int j = id;
            int dd = j >> 10, m = j & 1023;
            embT[j] = ldf(emb, m * 64 + dd, isf);
            j = id + 32768;
            dd = j >> 10; m = j & 1023;
            embT[j] = ldf(emb, m * 64 + dd, isf);
        }
        if (id < 1024){
            int n = id;
            float s1 = 0.f, s2 = 0.f;
            for (int dd = 0; dd < 64; dd++){
                float e = ldf(emb, n * 64 + dd, isf);
                s1 += e * ldf(aemi, dd, isf);
                s2 += e * ldf(aemj, dd, isf);
            }
            eai[n] = s1; eaj[n] = s2;
            float sq = 0.f;
            if (!isf){
                const uint4* pm = (const uint4*)((const unsigned short*)emb + n * 64);
                #pragma unroll
                for (int i = 0; i < 8; i++){
                    uint4 ww = pm[i];
                    float a0,a1,a2,a3,a4,a5,a6,a7;
                    unpack2(ww.x,a0,a1); unpack2(ww.y,a2,a3); unpack2(ww.z,a4,a5); unpack2(ww.w,a6,a7);
                    sq += a0*a0 + a1*a1 + a2*a2 + a3*a3 + a4*a4 + a5*a5 + a6*a6 + a7*a7;
                }
            } else {
                const float4* pm = (const float4*)((const float*)emb + n * 64);
                #pragma unroll
                for (int i = 0; i < 16; i++){
                    float4 ww = pm[i];
                    sq += ww.x*ww.x + ww.y*ww.y + ww.z*ww.z + ww.w*ww.w;
                }
            }
            rsqm[n] = rsqrtf(sq);
        }
    }
    // k1a: partials for per-(b,n) mean/var. b = blk>>4, lq = blk&15
    int b = blockIdx.x >> 4, lq = blockIdx.x & 15;
    int n0 = t * 4;
    size_t base = (size_t)b * LNSZ + (size_t)(lq * 32) * NNODES + n0;
    float s0=0,s1=0,s2=0,s3=0,q0=0,q1=0,q2=0,q3=0;
    if (isf){
        const float* p = (const float*)x + base;
        for (int i = 0; i < 32; i++){
            float4 w = *(const float4*)p;
            s0+=w.x; q0+=w.x*w.x; s1+=w.y; q1+=w.y*w.y;
            s2+=w.z; q2+=w.z*w.z; s3+=w.w; q3+=w.w*w.w;
            p += NNODES;
        }
    } else {
        const unsigned short* p = (const unsigned short*)x + base;
        for (int i = 0; i < 32; i++){
            uint2 w = *(const uint2*)p;
            float a,bv,c,d2;
            unpack2(w.x, a, bv); unpack2(w.y, c, d2);
            s0+=a; q0+=a*a; s1+=bv; q1+=bv*bv; s2+=c; q2+=c*c; s3+=d2; q3+=d2*d2;
            p += NNODES;
        }
    }
    int v = b * NNODES + n0;
    float2* pp = (float2*)part;
    pp[(size_t)v*16 + lq]       = make_float2(s0,q0);
    pp[(size_t)(v+1)*16 + lq]   = make_float2(s1,q1);
    pp[(size_t)(v+2)*16 + lq]   = make_float2(s2,q2);
    pp[(size_t)(v+3)*16 + lq]   = make_float2(s3,q3);
}

// K13: k3 cos+top20 (all 1024 blocks; bit-identical trees to round 8) + k1b (blocks < 128).
__global__ void __launch_bounds__(256) k13_topk(const void* emb, const float* embT, const float* rsqm,
                                                int* topk, const void* x, const float* part,
                                                float* mr, float* outp){
    __shared__ float enf[64];
    __shared__ float n2s;
    __shared__ float crow[1024];
    int isf = detect_isf(x);
    int wave = threadIdx.x >> 6, lane = threadIdx.x & 63;
    int n = blockIdx.x;
    // k1b side duty
    if (blockIdx.x < 128){
        int v = blockIdx.x * 256 + threadIdx.x;
        const float2* pp = (const float2*)part + (size_t)v * 16;
        float s = 0.f, q = 0.f;
        for (int i = 0; i < 16; i++){ float2 w = pp[i]; s += w.x; q += w.y; }
        float mean = s * (1.f/512.f);
        float var  = q * (1.f/512.f) - mean * mean;
        float rstd = var > 0.f ? rsqrtf(var) : 0.f;   // var==0 -> nan_to_num -> 0
        ((float2*)mr)[v] = make_float2(mean, rstd);
        int b = v >> 10, nn = v & 1023;
        float xv = ldf(x, (int)((size_t)b * LNSZ + (size_t)511 * NNODES + nn), isf);
        outp[NTOT + v] = (xv - mean) * rstd;
    }
    if (wave == 0){
        float e = ldf(emb, n * 64 + lane, isf);
        enf[lane] = e;
        float p1 = e * e;
        #pragma unroll
        for (int m = 1; m < 64; m <<= 1) p1 += __shfl_xor(p1, m, 64);
        if (lane == 0) n2s = p1;
    }
    __syncthreads();
    float rn_own = rsqrtf(n2s);
    const float* en = enf;
    int mb = wave * 256 + lane * 4;
    float dot0 = 0.f, dot1 = 0.f, dot2 = 0.f, dot3 = 0.f;
    if (!isf){
        #pragma unroll
        for (int i = 0; i < 8; i++){
            float4 a0 = *(const float4*)(embT + (i*8+0)*1024 + mb);
            float4 a1 = *(const float4*)(embT + (i*8+1)*1024 + mb);
            float4 a2 = *(const float4*)(embT + (i*8+2)*1024 + mb);
            float4 a3 = *(const float4*)(embT + (i*8+3)*1024 + mb);
            float4 a4 = *(const float4*)(embT + (i*8+4)*1024 + mb);
            float4 a5 = *(const float4*)(embT + (i*8+5)*1024 + mb);
            float4 a6 = *(const float4*)(embT + (i*8+6)*1024 + mb);
            float4 a7 = *(const float4*)(embT + (i*8+7)*1024 + mb);
            const float* e8 = en + i * 8;
            dot0 += e8[0]*a0.x + e8[1]*a1.x + e8[2]*a2.x + e8[3]*a3.x
                  + e8[4]*a4.x + e8[5]*a5.x + e8[6]*a6.x + e8[7]*a7.x;
            dot1 += e8[0]*a0.y + e8[1]*a1.y + e8[2]*a2.y + e8[3]*a3.y
                  + e8[4]*a4.y + e8[5]*a5.y + e8[6]*a6.y + e8[7]*a7.y;
            dot2 += e8[0]*a0.z + e8[1]*a1.z + e8[2]*a2.z + e8[3]*a3.z
                  + e8[4]*a4.z + e8[5]*a5.z + e8[6]*a6.z + e8[7]*a7.z;
            dot3 += e8[0]*a0.w + e8[1]*a1.w + e8[2]*a2.w + e8[3]*a3.w
                  + e8[4]*a4.w + e8[5]*a5.w + e8[6]*a6.w + e8[7]*a7.w;
        }
    } else {
        #pragma unroll
        for (int i = 0; i < 16; i++){
            float4 a0 = *(const float4*)(embT + (i*4+0)*1024 + mb);
            float4 a1 = *(const float4*)(embT + (i*4+1)*1024 + mb);
            float4 a2 = *(const float4*)(embT + (i*4+2)*1024 + mb);
            float4 a3 = *(const float4*)(embT + (i*4+3)*1024 + mb);
            const float* e4 = en + i * 4;
            dot0 += e4[0]*a0.x + e4[1]*a1.x + e4[2]*a2.x + e4[3]*a3.x;
            dot1 += e4[0]*a0.y + e4[1]*a1.y + e4[2]*a2.y + e4[3]*a3.y;
            dot2 += e4[0]*a0.z + e4[1]*a1.z + e4[2]*a2.z + e4[3]*a3.z;
            dot3 += e4[0]*a0.w + e4[1]*a1.w + e4[2]*a2.w + e4[3]*a3.w;
        }
    }
    crow[mb+0] = dot0 * rn_own * rsqm[mb+0];
    crow[mb+1] = dot1 * rn_own * rsqm[mb+1];
    crow[mb+2] = dot2 * rn_own * rsqm[mb+2];
    crow[mb+3] = dot3 * rn_own * rsqm[mb+3];
    __syncthreads();
    if (wave != 0) return;
    float va[16];
    #pragma unroll
    for (int ii = 0; ii < 16; ii++) va[ii] = crow[ii * 64 + lane];
    for (int k = 0; k < TOPK; k++){
        float t8[8]; int x8[8];
        #pragma unroll
        for (int j = 0; j < 8; j++){
            bool c = va[2*j+1] > va[2*j];
            t8[j] = c ? va[2*j+1] : va[2*j]; x8[j] = c ? 2*j+1 : 2*j;
        }
        #pragma unroll
        for (int j = 0; j < 4; j++){
            bool c = t8[2*j+1] > t8[2*j];
            t8[j] = c ? t8[2*j+1] : t8[2*j]; x8[j] = c ? x8[2*j+1] : x8[2*j];
        }
        #pragma unroll
        for (int j = 0; j < 2; j++){
            bool c = t8[2*j+1] > t8[2*j];
            t8[j] = c ? t8[2*j+1] : t8[2*j]; x8[j] = c ? x8[2*j+1] : x8[2*j];
        }
        bool c0 = t8[1] > t8[0];
        float bv = c0 ? t8[1] : t8[0]; int bi = c0 ? x8[1] : x8[0];
        int bm = bi * 64 + lane;
        #pragma unroll
        for (int s = 1; s < 64; s <<= 1){
            float ov = __shfl_xor(bv, s, 64);
            int   om = __shfl_xor(bm, s, 64);
            bool u = (ov > bv) || (ov == bv && om < bm);   // tie -> lower m (jax top_k)
            bv = u ? ov : bv; bm = u ? om : bm;
        }
        if (lane == 0) topk[n * TOPK + k] = bm;
        int evi = bm >> 6;
        bool own = ((bm & 63) == lane);
        #pragma unroll
        for (int ii = 0; ii < 16; ii++)
            va[ii] = (own && ii == evi) ? -__builtin_inff() : va[ii];
    }
}

// K2: MFMA GEMM h = Xnorm @ lin_W + fused ai/aj epilogue. grid 512.
__global__ void __launch_bounds__(256) k2_gemm_h(const void* x, const unsigned short* wt,
                                                const float* mr, float* h,
                                                const void* atti, const void* attj,
                                                const float* eai, const float* eaj,
                                                float* ai, float* aj){
    __shared__ unsigned short A_l[64 * 136];
    __shared__ unsigned short W_l[64 * 136];
    __shared__ float4 colp4[256];
    int isf = detect_isf(x);
    int t = threadIdx.x;
    int q = blockIdx.x & 63, mtile = blockIdx.x >> 6;
    int b = q >> 1, nbase = (q & 1) * 512;
    size_t xbase = (size_t)b * LNSZ + nbase;

    colp4[t] = ((const float4*)mr)[q * 256 + t];

    int wave = t >> 6, lane = t & 63;
    int quad = lane >> 4, lcol = lane & 15;
    floatx4 acc[4];
    for (int j = 0; j < 4; j++) acc[j] = (floatx4){0.f,0.f,0.f,0.f};
    __syncthreads();

    for (int kc = 0; kc < 4; kc++){
        for (int i = 0; i < 4; i++){
            int id = i * 256 + t;
            int l = id >> 4, c16 = id & 15;
            int lg = mtile * 64 + l;
            uint4 o;
            if (lg == 511){
                o = make_uint4(0u, 0u, 0u, 0u);
            } else {
                size_t ofs = xbase + (size_t)lg * NNODES + kc * 128 + c16 * 8;
                float e0,e1,e2,e3,e4,e5,e6,e7;
                if (isf){
                    const float4* px = (const float4*)((const float*)x + ofs);
                    float4 wa = px[0], wb = px[1];
                    e0=wa.x; e1=wa.y; e2=wa.z; e3=wa.w; e4=wb.x; e5=wb.y; e6=wb.z; e7=wb.w;
                } else {
                    uint4 w = *(const uint4*)((const unsigned short*)x + ofs);
                    unpack2(w.x,e0,e1); unpack2(w.y,e2,e3); unpack2(w.z,e4,e5); unpack2(w.w,e6,e7);
                }
                int f4b = kc * 64 + c16 * 4;
                float4 pA = colp4[f4b+0], pB = colp4[f4b+1], pC = colp4[f4b+2], pD = colp4[f4b+3];
                e0 = (e0 - pA.x) * pA.y;  e1 = (e1 - pA.z) * pA.w;
                e2 = (e2 - pB.x) * pB.y;  e3 = (e3 - pB.z) * pB.w;
                e4 = (e4 - pC.x) * pC.y;  e5 = (e5 - pC.z) * pC.w;
                e6 = (e6 - pD.x) * pD.y;  e7 = (e7 - pD.z) * pD.w;
                o.x = (unsigned)f2bf(e0) | ((unsigned)f2bf(e1) << 16);
                o.y = (unsigned)f2bf(e2) | ((unsigned)f2bf(e3) << 16);
                o.z = (unsigned)f2bf(e4) | ((unsigned)f2bf(e5) << 16);
                o.w = (unsigned)f2bf(e6) | ((unsigned)f2bf(e7) << 16);
            }
            *(uint4*)&A_l[l * 136 + c16 * 8] = o;
        }
        for (int i = 0; i < 4; i++){
            int id = i * 256 + t;
            int dd = id >> 4, c16 = id & 15;
            uint4 w = *(const uint4*)(wt + dd * 512 + kc * 128 + c16 * 8);
            *(uint4*)&W_l[dd * 136 + c16 * 8] = w;
        }
        __syncthreads();
        for (int ks = 0; ks < 4; ks++){
            short8 af, bfr[4];
            af = *(const short8*)&A_l[(wave * 16 + lcol) * 136 + ks * 32 + quad * 8];
            for (int tc = 0; tc < 4; tc++)
                bfr[tc] = *(const short8*)&W_l[(tc * 16 + lcol) * 136 + ks * 32 + quad * 8];
            for (int tc = 0; tc < 4; tc++)
                acc[tc] = __builtin_amdgcn_mfma_f32_16x16x32_bf16(af, bfr[tc], acc[tc], 0, 0, 0);
        }
        __syncthreads();
    }
    // fused ai/aj: per-row dot with att_i/att_j from accumulators (smooth path)
    float aw[4], jw[4];
    #pragma unroll
    for (int tc = 0; tc < 4; tc++){
        int dcol = tc * 16 + lcol;
        aw[tc] = ldf(atti, dcol, isf);
        jw[tc] = ldf(attj, dcol, isf);
    }
    #pragma unroll
    for (int r = 0; r < 4; r++){
        float pi = 0.f, pj = 0.f;
        #pragma unroll
        for (int tc = 0; tc < 4; tc++){
            float hv = acc[tc][r];
            pi += hv * aw[tc];
            pj += hv * jw[tc];
        }
        #pragma unroll
        for (int s = 1; s < 16; s <<= 1){
            pi += __shfl_xor(pi, s, 64);
            pj += __shfl_xor(pj, s, 64);
        }
        if (lcol == 0){
            int lrow = wave * 16 + quad * 4 + r;
            int row = (mtile * 64 + lrow) * 64 + q;
            int n = row & 1023;
            ai[row] = pi + eai[n];
            aj[row] = pj + eaj[n];
        }
    }
    // h writes
    for (int tc = 0; tc < 4; tc++){
        int dcol = tc * 16 + lcol;
        for (int r = 0; r < 4; r++){
            int lrow = wave * 16 + quad * 4 + r;
            int row = (mtile * 64 + lrow) * 64 + q;
            h[(size_t)row * 64 + dcol] = acc[tc][r];
        }
    }
}

// K5: attention softmax + aggregation + fused BN1 stats. grid 2048, 4 nodes per wave.
__global__ void __launch_bounds__(256) k5_attn(const float* h, const float* ai, const float* aj, const int* topk,
                                               const void* gnn_b, float* out, float* stats1, const void* x){
    __shared__ float bs[256], bq[256];
    int isf = detect_isf(x);
    int wave = threadIdx.x >> 6, lane = threadIdx.x & 63;
    float gb = ldf(gnn_b, lane, isf);
    float ssum = 0.f, ssq = 0.f;
    int v0 = (blockIdx.x * 4 + wave) * 4;
    #pragma unroll
    for (int i = 0; i < 4; i++){
        int v = v0 + i;
        int n = v & 1023, bbase = v & ~1023;
        int srcv; bool valid;
        if (lane < TOPK){
            int id = topk[n * TOPK + lane];
            srcv = bbase | id;
            valid = (id != n);
        } else if (lane == TOPK){
            srcv = v; valid = true;
        } else { srcv = v; valid = false; }
        float l = ai[v] + aj[srcv];
        l = (l >= 0.f) ? l : 0.2f * l;
        if (!valid) l = -__builtin_inff();
        float m = l;
        #pragma unroll
        for (int s = 1; s < 64; s <<= 1){ float o = __shfl_xor(m, s, 64); m = fmaxf(m, o); }
        float ev = valid ? __expf(l - m) : 0.f;
        float dsum = ev;
        #pragma unroll
        for (int s = 1; s < 64; s <<= 1) dsum += __shfl_xor(dsum, s, 64);
        float rd = 1.f / dsum;
        float acc = 0.f;
        #pragma unroll
        for (int j = 0; j <= TOPK; j++){
            float e = __shfl(ev, j, 64);
            int  sj = __shfl(srcv, j, 64);
            acc += e * h[(size_t)sj * 64 + lane];
        }
        float res = acc * rd + gb;
        out[(size_t)v * 64 + lane] = res;
        ssum += res; ssq += res * res;
    }
    bs[threadIdx.x] = ssum; bq[threadIdx.x] = ssq;
    __syncthreads();
    if (wave == 0){
        float s  = bs[lane] + bs[64+lane] + bs[128+lane] + bs[192+lane];
        float qq = bq[lane] + bq[64+lane] + bq[128+lane] + bq[192+lane];
        atomicAdd(&stats1[lane], s);
        atomicAdd(&stats1[64 + lane], qq);
    }
}

// K6: BN1 + relu + *emb, accumulate BN2 stats. grid 512
__global__ void __launch_bounds__(256) k6_stats2(const float* out, const float* stats1, const void* g1,
                                                 const void* b1, const void* emb,
                                                 float* stats2, const void* x){
    __shared__ float bs[256], bq[256];
    int isf = detect_isf(x);
    int wave = threadIdx.x >> 6, lane = threadIdx.x & 63;
    float mu   = stats1[lane] * (1.f/32768.f);
    float var  = stats1[64 + lane] * (1.f/32768.f) - mu * mu;
    float rstd = 1.f / sqrtf(var + 1e-5f);
    float g = ldf(g1, lane, isf), bb = ldf(b1, lane, isf);
    float ssum = 0.f, ssq = 0.f;
    int v0 = (blockIdx.x * 4 + wave) * 16;
    for (int i = 0; i < 16; i++){
        int v = v0 + i; int n = v & 1023;
        float xv = out[(size_t)v * 64 + lane];
        float y = fmaxf((xv - mu) * rstd * g + bb, 0.f);
        float z = y * ldf(emb, n * 64 + lane, isf);
        ssum += z; ssq += z * z;
    }
    bs[threadIdx.x] = ssum; bq[threadIdx.x] = ssq;
    __syncthreads();
    if (wave == 0){
        float s  = bs[lane] + bs[64+lane] + bs[128+lane] + bs[192+lane];
        float qq = bq[lane] + bq[64+lane] + bq[128+lane] + bq[192+lane];
        atomicAdd(&stats2[lane], s);
        atomicAdd(&stats2[64 + lane], qq);
    }
}

// K7: recompute z, BN2 + relu + dot(out_W) + out_b -> o (fp32). grid 512
__global__ void __launch_bounds__(256) k7_out(const float* out, const float* stats1, const float* stats2,
                                              const void* g1, const void* b1,
                                              const void* g2, const void* b2,
                                              const void* emb, const void* outw,
                                              const void* outb, float* o, const void* x){
    int isf = detect_isf(x);
    int wave = threadIdx.x >> 6, lane = threadIdx.x & 63;
    float mu1   = stats1[lane] * (1.f/32768.f);
    float var1  = stats1[64 + lane] * (1.f/32768.f) - mu1 * mu1;
    float rstd1 = 1.f / sqrtf(var1 + 1e-5f);
    float g1v = ldf(g1, lane, isf), b1v = ldf(b1, lane, isf);
    float mu2   = stats2[lane] * (1.f/32768.f);
    float var2  = stats2[64 + lane] * (1.f/32768.f) - mu2 * mu2;
    float rstd2 = 1.f / sqrtf(var2 + 1e-5f);
    float g2v = ldf(g2, lane, isf), b2v = ldf(b2, lane, isf);
    float w = ldf(outw, lane, isf);
    float ob = ldf(outb, 0, isf);
    int v0 = (blockIdx.x * 4 + wave) * 16;
    for (int i = 0; i < 16; i++){
        int v = v0 + i; int n = v & 1023;
        float xv = out[(size_t)v * 64 + lane];
        float z = fmaxf((xv - mu1) * rstd1 * g1v + b1v, 0.f) * ldf(emb, n * 64 + lane, isf);
        float y = fmaxf((z - mu2) * rstd2 * g2v + b2v, 0.f);
        float p = y * w;
        for (int s = 1; s < 64; s <<= 1) p += __shfl_xor(p, s, 64);
        if (lane == 0) o[v] = p + ob;
    }
}

extern "C" void kernel_launch(void* const* d_in, const int* in_sizes, int n_in,
                              void* d_out, int out_size, void* d_ws, size_t ws_size,
                              hipStream_t stream){
    const void* x    = d_in[0];
    const void* emb  = d_in[1];
    const void* linW = d_in[2];
    const void* atti = d_in[3];
    const void* attj = d_in[4];
    const void* aemi = d_in[5];
    const void* aemj = d_in[6];
    const void* gnnb = d_in[7];
    const void* g1   = d_in[8];
    const void* b1   = d_in[9];
    const void* g2   = d_in[10];
    const void* b2   = d_in[11];
    const void* outw = d_in[12];
    const void* outb = d_in[13];
    float* o = (float*)d_out;                 // fp32 outputs: [o(32768), gt(32768)]

    char* w = (char*)d_ws;
    float*          mr    = (float*)(w + 0);           // 256 KB
    unsigned short* wt    = (unsigned short*)(w + 262144); // 64 KB
    float*          h     = (float*)(w + 327680);      // 8 MB
    float*          eai   = (float*)(w + 8716288);     // 4 KB
    float*          eaj   = (float*)(w + 8720384);     // 4 KB
    int*            topk  = (int*)(w + 8724480);       // 80 KB
    float*          ai    = (float*)(w + 8806400);     // 128 KB
    float*          aj    = (float*)(w + 8937472);     // 128 KB
    float*          outg  = (float*)(w + 9068544);     // 8 MB region
    float*          part  = outg;                      // first 4 MB: k01 partials (consumed by k13)
    float*          embT  = (float*)(w + 13262848);    // 256 KB (upper outg half; lifetime k01->k13)
    float*          rsqm  = (float*)(w + 13524992);    // 4 KB   (same lifetime)
    float*          stats = (float*)(w + 17457152);    // 256 floats

    hipLaunchKernelGGL(k01_prep, dim3(512),  dim3(256), 0, stream, x, linW, wt, emb, aemi, aemj,
                       eai, eaj, embT, rsqm, part, stats);
    hipLaunchKernelGGL(k13_topk, dim3(1024), dim3(256), 0, stream, emb, embT, rsqm, topk, x, part, mr, o);
    hipLaunchKernelGGL(k2_gemm_h, dim3(512), dim3(256), 0, stream, x, wt, mr, h, atti, attj, eai, eaj, ai, aj);
    hipLaunchKernelGGL(k5_attn,  dim3(2048), dim3(256), 0, stream, h, ai, aj, topk, gnnb, outg, stats, x);
    hipLaunchKernelGGL(k6_stats2, dim3(512), dim3(256), 0, stream, outg, stats, g1, b1, emb, stats + 128, x);
    hipLaunchKernelGGL(k7_out,   dim3(512),  dim3(256), 0, stream, outg, stats, stats + 128,
                       g1, b1, g2, b2, emb, outw, outb, o, x);
}

// Round 10
// 233.030 us; speedup vs baseline: 1.1914x; 1.1914x over previous
//
#include <hip/hip_runtime.h>
#include <stdint.h>

#define BB 32
#define LL 512
#define NNODES 1024
#define DD 64
#define TOPK 20
#define NTOT (BB*NNODES)     // 32768
#define LNSZ (LL*NNODES)     // 524288

typedef short short8 __attribute__((ext_vector_type(8)));
typedef float floatx4 __attribute__((ext_vector_type(4)));

__device__ __forceinline__ float bf2f(unsigned short u){
    union { unsigned int i; float f; } x; x.i = ((unsigned int)u) << 16; return x.f;
}
__device__ __forceinline__ unsigned short f2bf(float f){
    union { float f; unsigned int i; } x; x.f = f;
    unsigned int u = x.i;
    return (unsigned short)((u + 0x7FFFu + ((u >> 16) & 1u)) >> 16);
}
__device__ __forceinline__ void unpack2(unsigned int w, float& lo, float& hi){
    union { unsigned int i; float f; } a, b;
    a.i = w << 16; b.i = w & 0xFFFF0000u;
    lo = a.f; hi = b.f;
}
__device__ __forceinline__ float ldf(const void* p, int i, int isf){
    return isf ? ((const float*)p)[i] : bf2f(((const unsigned short*)p)[i]);
}
// Inline per-wave dtype detection (1 = fp32). Same crazy-test as the old kd kernel;
// 64 fixed sample addresses -> L2-resident after first wave; deterministic per wave.
__device__ __forceinline__ int detect_isf(const void* xv){
    const unsigned short* x = (const unsigned short*)xv;
    int lane = threadIdx.x & 63;
    unsigned int idx = ((unsigned)lane * 131071u) & 0x7FFFFFu;
    float v = bf2f(x[idx * 2]);
    float a = fabsf(v);
    int crazy = (!(a <= 1e3f)) || (v != 0.f && a < 1e-6f);
    unsigned long long m = __ballot(crazy);
    return __popcll(m) > 16;
}

// K01: k1a partial sums (all 512 blocks) + prep duties (blocks < 128):
//   Wt transpose, embT (64x1024 fp32), rsqm (exact sq-tree), eai/eaj, stats zero (block 0).
__global__ void __launch_bounds__(256) k01_prep(const void* x, const void* lw, unsigned short* wt,
                                                const void* emb, const void* aemi, const void* aemj,
                                                float* eai, float* eaj, float* embT, float* rsqm,
                                                float* part, float* stats){
    int isf = detect_isf(x);
    int t = threadIdx.x;
    if (blockIdx.x == 0) stats[t] = 0.f;
    if (blockIdx.x < 128){
        int id = blockIdx.x * 256 + t;                // 0..32767
        int k = id >> 6, d = id & 63;
        unsigned short w = isf ? f2bf(((const float*)lw)[id]) : ((const unsigned short*)lw)[id];
        wt[d * 512 + k] = w;
        {
            int j = id;
            int dd = j >> 10, m = j & 1023;
            embT[j] = ldf(emb, m * 64 + dd, isf);
            j = id + 32768;
            dd = j >> 10; m = j & 1023;
            embT[j] = ldf(emb, m * 64 + dd, isf);
        }
        if (id < 1024){
            int n = id;
            float s1 = 0.f, s2 = 0.f;
            for (int dd = 0; dd < 64; dd++){
                float e = ldf(emb, n * 64 + dd, isf);
                s1 += e * ldf(aemi, dd, isf);
                s2 += e * ldf(aemj, dd, isf);
            }
            eai[n] = s1; eaj[n] = s2;
            float sq = 0.f;
            if (!isf){
                const uint4* pm = (const uint4*)((const unsigned short*)emb + n * 64);
                #pragma unroll
                for (int i = 0; i < 8; i++){
                    uint4 ww = pm[i];
                    float a0,a1,a2,a3,a4,a5,a6,a7;
                    unpack2(ww.x,a0,a1); unpack2(ww.y,a2,a3); unpack2(ww.z,a4,a5); unpack2(ww.w,a6,a7);
                    sq += a0*a0 + a1*a1 + a2*a2 + a3*a3 + a4*a4 + a5*a5 + a6*a6 + a7*a7;
                }
            } else {
                const float4* pm = (const float4*)((const float*)emb + n * 64);
                #pragma unroll
                for (int i = 0; i < 16; i++){
                    float4 ww = pm[i];
                    sq += ww.x*ww.x + ww.y*ww.y + ww.z*ww.z + ww.w*ww.w;
                }
            }
            rsqm[n] = rsqrtf(sq);
        }
    }
    // k1a: partials for per-(b,n) mean/var. b = blk>>4, lq = blk&15
    int b = blockIdx.x >> 4, lq = blockIdx.x & 15;
    int n0 = t * 4;
    size_t base = (size_t)b * LNSZ + (size_t)(lq * 32) * NNODES + n0;
    float s0=0,s1=0,s2=0,s3=0,q0=0,q1=0,q2=0,q3=0;
    if (isf){
        const float* p = (const float*)x + base;
        for (int i = 0; i < 32; i++){
            float4 w = *(const float4*)p;
            s0+=w.x; q0+=w.x*w.x; s1+=w.y; q1+=w.y*w.y;
            s2+=w.z; q2+=w.z*w.z; s3+=w.w; q3+=w.w*w.w;
            p += NNODES;
        }
    } else {
        const unsigned short* p = (const unsigned short*)x + base;
        for (int i = 0; i < 32; i++){
            uint2 w = *(const uint2*)p;
            float a,bv,c,d2;
            unpack2(w.x, a, bv); unpack2(w.y, c, d2);
            s0+=a; q0+=a*a; s1+=bv; q1+=bv*bv; s2+=c; q2+=c*c; s3+=d2; q3+=d2*d2;
            p += NNODES;
        }
    }
    int v = b * NNODES + n0;
    float2* pp = (float2*)part;
    pp[(size_t)v*16 + lq]       = make_float2(s0,q0);
    pp[(size_t)(v+1)*16 + lq]   = make_float2(s1,q1);
    pp[(size_t)(v+2)*16 + lq]   = make_float2(s2,q2);
    pp[(size_t)(v+3)*16 + lq]   = make_float2(s3,q3);
}

// K13: k3 cos+top20 (all 1024 blocks; bit-identical trees) + k1b (blocks < 128).
__global__ void __launch_bounds__(256) k13_topk(const void* emb, const float* embT, const float* rsqm,
                                                int* topk, const void* x, const float* part,
                                                float* mr, float* outp){
    __shared__ float enf[64];
    __shared__ float n2s;
    __shared__ float crow[1024];
    int isf = detect_isf(x);
    int wave = threadIdx.x >> 6, lane = threadIdx.x & 63;
    int n = blockIdx.x;
    // k1b side duty
    if (blockIdx.x < 128){
        int v = blockIdx.x * 256 + threadIdx.x;
        const float2* pp = (const float2*)part + (size_t)v * 16;
        float s = 0.f, q = 0.f;
        for (int i = 0; i < 16; i++){ float2 w = pp[i]; s += w.x; q += w.y; }
        float mean = s * (1.f/512.f);
        float var  = q * (1.f/512.f) - mean * mean;
        float rstd = var > 0.f ? rsqrtf(var) : 0.f;   // var==0 -> nan_to_num -> 0
        ((float2*)mr)[v] = make_float2(mean, rstd);
        int b = v >> 10, nn = v & 1023;
        float xv = ldf(x, (int)((size_t)b * LNSZ + (size_t)511 * NNODES + nn), isf);
        outp[NTOT + v] = (xv - mean) * rstd;
    }
    if (wave == 0){
        float e = ldf(emb, n * 64 + lane, isf);
        enf[lane] = e;
        float p1 = e * e;
        #pragma unroll
        for (int m = 1; m < 64; m <<= 1) p1 += __shfl_xor(p1, m, 64);
        if (lane == 0) n2s = p1;
    }
    __syncthreads();
    float rn_own = rsqrtf(n2s);
    const float* en = enf;
    int mb = wave * 256 + lane * 4;
    float dot0 = 0.f, dot1 = 0.f, dot2 = 0.f, dot3 = 0.f;
    if (!isf){
        #pragma unroll
        for (int i = 0; i < 8; i++){
            float4 a0 = *(const float4*)(embT + (i*8+0)*1024 + mb);
            float4 a1 = *(const float4*)(embT + (i*8+1)*1024 + mb);
            float4 a2 = *(const float4*)(embT + (i*8+2)*1024 + mb);
            float4 a3 = *(const float4*)(embT + (i*8+3)*1024 + mb);
            float4 a4 = *(const float4*)(embT + (i*8+4)*1024 + mb);
            float4 a5 = *(const float4*)(embT + (i*8+5)*1024 + mb);
            float4 a6 = *(const float4*)(embT + (i*8+6)*1024 + mb);
            float4 a7 = *(const float4*)(embT + (i*8+7)*1024 + mb);
            const float* e8 = en + i * 8;
            dot0 += e8[0]*a0.x + e8[1]*a1.x + e8[2]*a2.x + e8[3]*a3.x
                  + e8[4]*a4.x + e8[5]*a5.x + e8[6]*a6.x + e8[7]*a7.x;
            dot1 += e8[0]*a0.y + e8[1]*a1.y + e8[2]*a2.y + e8[3]*a3.y
                  + e8[4]*a4.y + e8[5]*a5.y + e8[6]*a6.y + e8[7]*a7.y;
            dot2 += e8[0]*a0.z + e8[1]*a1.z + e8[2]*a2.z + e8[3]*a3.z
                  + e8[4]*a4.z + e8[5]*a5.z + e8[6]*a6.z + e8[7]*a7.z;
            dot3 += e8[0]*a0.w + e8[1]*a1.w + e8[2]*a2.w + e8[3]*a3.w
                  + e8[4]*a4.w + e8[5]*a5.w + e8[6]*a6.w + e8[7]*a7.w;
        }
    } else {
        #pragma unroll
        for (int i = 0; i < 16; i++){
            float4 a0 = *(const float4*)(embT + (i*4+0)*1024 + mb);
            float4 a1 = *(const float4*)(embT + (i*4+1)*1024 + mb);
            float4 a2 = *(const float4*)(embT + (i*4+2)*1024 + mb);
            float4 a3 = *(const float4*)(embT + (i*4+3)*1024 + mb);
            const float* e4 = en + i * 4;
            dot0 += e4[0]*a0.x + e4[1]*a1.x + e4[2]*a2.x + e4[3]*a3.x;
            dot1 += e4[0]*a0.y + e4[1]*a1.y + e4[2]*a2.y + e4[3]*a3.y;
            dot2 += e4[0]*a0.z + e4[1]*a1.z + e4[2]*a2.z + e4[3]*a3.z;
            dot3 += e4[0]*a0.w + e4[1]*a1.w + e4[2]*a2.w + e4[3]*a3.w;
        }
    }
    crow[mb+0] = dot0 * rn_own * rsqm[mb+0];
    crow[mb+1] = dot1 * rn_own * rsqm[mb+1];
    crow[mb+2] = dot2 * rn_own * rsqm[mb+2];
    crow[mb+3] = dot3 * rn_own * rsqm[mb+3];
    __syncthreads();
    if (wave != 0) return;
    float va[16];
    #pragma unroll
    for (int ii = 0; ii < 16; ii++) va[ii] = crow[ii * 64 + lane];
    for (int k = 0; k < TOPK; k++){
        float t8[8]; int x8[8];
        #pragma unroll
        for (int j = 0; j < 8; j++){
            bool c = va[2*j+1] > va[2*j];
            t8[j] = c ? va[2*j+1] : va[2*j]; x8[j] = c ? 2*j+1 : 2*j;
        }
        #pragma unroll
        for (int j = 0; j < 4; j++){
            bool c = t8[2*j+1] > t8[2*j];
            t8[j] = c ? t8[2*j+1] : t8[2*j]; x8[j] = c ? x8[2*j+1] : x8[2*j];
        }
        #pragma unroll
        for (int j = 0; j < 2; j++){
            bool c = t8[2*j+1] > t8[2*j];
            t8[j] = c ? t8[2*j+1] : t8[2*j]; x8[j] = c ? x8[2*j+1] : x8[2*j];
        }
        bool c0 = t8[1] > t8[0];
        float bv = c0 ? t8[1] : t8[0]; int bi = c0 ? x8[1] : x8[0];
        int bm = bi * 64 + lane;
        #pragma unroll
        for (int s = 1; s < 64; s <<= 1){
            float ov = __shfl_xor(bv, s, 64);
            int   om = __shfl_xor(bm, s, 64);
            bool u = (ov > bv) || (ov == bv && om < bm);   // tie -> lower m (jax top_k)
            bv = u ? ov : bv; bm = u ? om : bm;
        }
        if (lane == 0) topk[n * TOPK + k] = bm;
        int evi = bm >> 6;
        bool own = ((bm & 63) == lane);
        #pragma unroll
        for (int ii = 0; ii < 16; ii++)
            va[ii] = (own && ii == evi) ? -__builtin_inff() : va[ii];
    }
}

// K2: MFMA GEMM h = Xnorm @ lin_W + fused ai/aj epilogue. grid 512.
__global__ void __launch_bounds__(256) k2_gemm_h(const void* x, const unsigned short* wt,
                                                const float* mr, float* h,
                                                const void* atti, const void* attj,
                                                const float* eai, const float* eaj,
                                                float* ai, float* aj){
    __shared__ unsigned short A_l[64 * 136];
    __shared__ unsigned short W_l[64 * 136];
    __shared__ float4 colp4[256];
    int isf = detect_isf(x);
    int t = threadIdx.x;
    int q = blockIdx.x & 63, mtile = blockIdx.x >> 6;
    int b = q >> 1, nbase = (q & 1) * 512;
    size_t xbase = (size_t)b * LNSZ + nbase;

    colp4[t] = ((const float4*)mr)[q * 256 + t];

    int wave = t >> 6, lane = t & 63;
    int quad = lane >> 4, lcol = lane & 15;
    floatx4 acc[4];
    for (int j = 0; j < 4; j++) acc[j] = (floatx4){0.f,0.f,0.f,0.f};
    __syncthreads();

    for (int kc = 0; kc < 4; kc++){
        for (int i = 0; i < 4; i++){
            int id = i * 256 + t;
            int l = id >> 4, c16 = id & 15;
            int lg = mtile * 64 + l;
            uint4 o;
            if (lg == 511){
                o = make_uint4(0u, 0u, 0u, 0u);
            } else {
                size_t ofs = xbase + (size_t)lg * NNODES + kc * 128 + c16 * 8;
                float e0,e1,e2,e3,e4,e5,e6,e7;
                if (isf){
                    const float4* px = (const float4*)((const float*)x + ofs);
                    float4 wa = px[0], wb = px[1];
                    e0=wa.x; e1=wa.y; e2=wa.z; e3=wa.w; e4=wb.x; e5=wb.y; e6=wb.z; e7=wb.w;
                } else {
                    uint4 w = *(const uint4*)((const unsigned short*)x + ofs);
                    unpack2(w.x,e0,e1); unpack2(w.y,e2,e3); unpack2(w.z,e4,e5); unpack2(w.w,e6,e7);
                }
                int f4b = kc * 64 + c16 * 4;
                float4 pA = colp4[f4b+0], pB = colp4[f4b+1], pC = colp4[f4b+2], pD = colp4[f4b+3];
                e0 = (e0 - pA.x) * pA.y;  e1 = (e1 - pA.z) * pA.w;
                e2 = (e2 - pB.x) * pB.y;  e3 = (e3 - pB.z) * pB.w;
                e4 = (e4 - pC.x) * pC.y;  e5 = (e5 - pC.z) * pC.w;
                e6 = (e6 - pD.x) * pD.y;  e7 = (e7 - pD.z) * pD.w;
                o.x = (unsigned)f2bf(e0) | ((unsigned)f2bf(e1) << 16);
                o.y = (unsigned)f2bf(e2) | ((unsigned)f2bf(e3) << 16);
                o.z = (unsigned)f2bf(e4) | ((unsigned)f2bf(e5) << 16);
                o.w = (unsigned)f2bf(e6) | ((unsigned)f2bf(e7) << 16);
            }
            *(uint4*)&A_l[l * 136 + c16 * 8] = o;
        }
        for (int i = 0; i < 4; i++){
            int id = i * 256 + t;
            int dd = id >> 4, c16 = id & 15;
            uint4 w = *(const uint4*)(wt + dd * 512 + kc * 128 + c16 * 8);
            *(uint4*)&W_l[dd * 136 + c16 * 8] = w;
        }
        __syncthreads();
        for (int ks = 0; ks < 4; ks++){
            short8 af, bfr[4];
            af = *(const short8*)&A_l[(wave * 16 + lcol) * 136 + ks * 32 + quad * 8];
            for (int tc = 0; tc < 4; tc++)
                bfr[tc] = *(const short8*)&W_l[(tc * 16 + lcol) * 136 + ks * 32 + quad * 8];
            for (int tc = 0; tc < 4; tc++)
                acc[tc] = __builtin_amdgcn_mfma_f32_16x16x32_bf16(af, bfr[tc], acc[tc], 0, 0, 0);
        }
        __syncthreads();
    }
    // fused ai/aj epilogue (smooth path)
    float aw[4], jw[4];
    #pragma unroll
    for (int tc = 0; tc < 4; tc++){
        int dcol = tc * 16 + lcol;
        aw[tc] = ldf(atti, dcol, isf);
        jw[tc] = ldf(attj, dcol, isf);
    }
    #pragma unroll
    for (int r = 0; r < 4; r++){
        float pi = 0.f, pj = 0.f;
        #pragma unroll
        for (int tc = 0; tc < 4; tc++){
            float hv = acc[tc][r];
            pi += hv * aw[tc];
            pj += hv * jw[tc];
        }
        #pragma unroll
        for (int s = 1; s < 16; s <<= 1){
            pi += __shfl_xor(pi, s, 64);
            pj += __shfl_xor(pj, s, 64);
        }
        if (lcol == 0){
            int lrow = wave * 16 + quad * 4 + r;
            int row = (mtile * 64 + lrow) * 64 + q;
            int n = row & 1023;
            ai[row] = pi + eai[n];
            aj[row] = pj + eaj[n];
        }
    }
    for (int tc = 0; tc < 4; tc++){
        int dcol = tc * 16 + lcol;
        for (int r = 0; r < 4; r++){
            int lrow = wave * 16 + quad * 4 + r;
            int row = (mtile * 64 + lrow) * 64 + q;
            h[(size_t)row * 64 + dcol] = acc[tc][r];
        }
    }
}

// K5: attention softmax + aggregation. grid 8192, ONE node per wave (32768 waves, 4x oversub —
// round-9 post-mortem: 4 nodes/wave at 1x capacity exposed the gather latency; this form is proven).
__global__ void __launch_bounds__(256) k5_attn(const float* h, const float* ai, const float* aj, const int* topk,
                                               const void* gnn_b, float* out, const void* x){
    int isf = detect_isf(x);
    int wave = threadIdx.x >> 6, lane = threadIdx.x & 63;
    float gb = ldf(gnn_b, lane, isf);
    int v = blockIdx.x * 4 + wave;
    int n = v & 1023, bbase = v & ~1023;
    int srcv; bool valid;
    if (lane < TOPK){
        int id = topk[n * TOPK + lane];
        srcv = bbase | id;
        valid = (id != n);                      // topk self-edge is masked
    } else if (lane == TOPK){
        srcv = v; valid = true;                 // appended self-loop (not masked)
    } else { srcv = v; valid = false; }
    float l = ai[v] + aj[srcv];
    l = (l >= 0.f) ? l : 0.2f * l;              // leaky relu before mask
    if (!valid) l = -__builtin_inff();
    float m = l;
    #pragma unroll
    for (int s = 1; s < 64; s <<= 1){ float o = __shfl_xor(m, s, 64); m = fmaxf(m, o); }
    float ev = valid ? __expf(l - m) : 0.f;
    float dsum = ev;
    #pragma unroll
    for (int s = 1; s < 64; s <<= 1) dsum += __shfl_xor(dsum, s, 64);
    float rd = 1.f / dsum;
    float acc = 0.f;
    #pragma unroll
    for (int j = 0; j <= TOPK; j++){
        float e = __shfl(ev, j, 64);
        int  sj = __shfl(srcv, j, 64);
        acc += e * h[(size_t)sj * 64 + lane];
    }
    out[(size_t)v * 64 + lane] = acc * rd + gb;
}

// K5b: BN1 stats over outg. grid 256 (128 nodes per block)
__global__ void __launch_bounds__(256) k5b_stats(const float* out, float* stats1){
    __shared__ float bs[256], bq[256];
    int wave = threadIdx.x >> 6, lane = threadIdx.x & 63;
    int v0 = blockIdx.x * 128 + wave * 32;
    float ssum = 0.f, ssq = 0.f;
    for (int i = 0; i < 32; i++){
        float x = out[(size_t)(v0 + i) * 64 + lane];
        ssum += x; ssq += x * x;
    }
    bs[threadIdx.x] = ssum; bq[threadIdx.x] = ssq;
    __syncthreads();
    if (wave == 0){
        float s  = bs[lane] + bs[64+lane] + bs[128+lane] + bs[192+lane];
        float qq = bq[lane] + bq[64+lane] + bq[128+lane] + bq[192+lane];
        atomicAdd(&stats1[lane], s);
        atomicAdd(&stats1[64 + lane], qq);
    }
}

// K6: BN1 + relu + *emb, accumulate BN2 stats. grid 512
__global__ void __launch_bounds__(256) k6_stats2(const float* out, const float* stats1, const void* g1,
                                                 const void* b1, const void* emb,
                                                 float* stats2, const void* x){
    __shared__ float bs[256], bq[256];
    int isf = detect_isf(x);
    int wave = threadIdx.x >> 6, lane = threadIdx.x & 63;
    float mu   = stats1[lane] * (1.f/32768.f);
    float var  = stats1[64 + lane] * (1.f/32768.f) - mu * mu;
    float rstd = 1.f / sqrtf(var + 1e-5f);
    float g = ldf(g1, lane, isf), bb = ldf(b1, lane, isf);
    float ssum = 0.f, ssq = 0.f;
    int v0 = (blockIdx.x * 4 + wave) * 16;
    for (int i = 0; i < 16; i++){
        int v = v0 + i; int n = v & 1023;
        float xv = out[(size_t)v * 64 + lane];
        float y = fmaxf((xv - mu) * rstd * g + bb, 0.f);
        float z = y * ldf(emb, n * 64 + lane, isf);
        ssum += z; ssq += z * z;
    }
    bs[threadIdx.x] = ssum; bq[threadIdx.x] = ssq;
    __syncthreads();
    if (wave == 0){
        float s  = bs[lane] + bs[64+lane] + bs[128+lane] + bs[192+lane];
        float qq = bq[lane] + bq[64+lane] + bq[128+lane] + bq[192+lane];
        atomicAdd(&stats2[lane], s);
        atomicAdd(&stats2[64 + lane], qq);
    }
}

// K7: recompute z, BN2 + relu + dot(out_W) + out_b -> o (fp32). grid 512
__global__ void __launch_bounds__(256) k7_out(const float* out, const float* stats1, const float* stats2,
                                              const void* g1, const void* b1,
                                              const void* g2, const void* b2,
                                              const void* emb, const void* outw,
                                              const void* outb, float* o, const void* x){
    int isf = detect_isf(x);
    int wave = threadIdx.x >> 6, lane = threadIdx.x & 63;
    float mu1   = stats1[lane] * (1.f/32768.f);
    float var1  = stats1[64 + lane] * (1.f/32768.f) - mu1 * mu1;
    float rstd1 = 1.f / sqrtf(var1 + 1e-5f);
    float g1v = ldf(g1, lane, isf), b1v = ldf(b1, lane, isf);
    float mu2   = stats2[lane] * (1.f/32768.f);
    float var2  = stats2[64 + lane] * (1.f/32768.f) - mu2 * mu2;
    float rstd2 = 1.f / sqrtf(var2 + 1e-5f);
    float g2v = ldf(g2, lane, isf), b2v = ldf(b2, lane, isf);
    float w = ldf(outw, lane, isf);
    float ob = ldf(outb, 0, isf);
    int v0 = (blockIdx.x * 4 + wave) * 16;
    for (int i = 0; i < 16; i++){
        int v = v0 + i; int n = v & 1023;
        float xv = out[(size_t)v * 64 + lane];
        float z = fmaxf((xv - mu1) * rstd1 * g1v + b1v, 0.f) * ldf(emb, n * 64 + lane, isf);
        float y = fmaxf((z - mu2) * rstd2 * g2v + b2v, 0.f);
        float p = y * w;
        for (int s = 1; s < 64; s <<= 1) p += __shfl_xor(p, s, 64);
        if (lane == 0) o[v] = p + ob;
    }
}

extern "C" void kernel_launch(void* const* d_in, const int* in_sizes, int n_in,
                              void* d_out, int out_size, void* d_ws, size_t ws_size,
                              hipStream_t stream){
    const void* x    = d_in[0];
    const void* emb  = d_in[1];
    const void* linW = d_in[2];
    const void* atti = d_in[3];
    const void* attj = d_in[4];
    const void* aemi = d_in[5];
    const void* aemj = d_in[6];
    const void* gnnb = d_in[7];
    const void* g1   = d_in[8];
    const void* b1   = d_in[9];
    const void* g2   = d_in[10];
    const void* b2   = d_in[11];
    const void* outw = d_in[12];
    const void* outb = d_in[13];
    float* o = (float*)d_out;                 // fp32 outputs: [o(32768), gt(32768)]

    char* w = (char*)d_ws;
    float*          mr    = (float*)(w + 0);           // 256 KB
    unsigned short* wt    = (unsigned short*)(w + 262144); // 64 KB
    float*          h     = (float*)(w + 327680);      // 8 MB
    float*          eai   = (float*)(w + 8716288);     // 4 KB
    float*          eaj   = (float*)(w + 8720384);     // 4 KB
    int*            topk  = (int*)(w + 8724480);       // 80 KB
    float*          ai    = (float*)(w + 8806400);     // 128 KB
    float*          aj    = (float*)(w + 8937472);     // 128 KB
    float*          outg  = (float*)(w + 9068544);     // 8 MB region
    float*          part  = outg;                      // first 4 MB: k01 partials (consumed by k13)
    float*          embT  = (float*)(w + 13262848);    // 256 KB (upper outg half; lifetime k01->k13)
    float*          rsqm  = (float*)(w + 13524992);    // 4 KB   (same lifetime)
    float*          stats = (float*)(w + 17457152);    // 256 floats

    hipLaunchKernelGGL(k01_prep, dim3(512),  dim3(256), 0, stream, x, linW, wt, emb, aemi, aemj,
                       eai, eaj, embT, rsqm, part, stats);
    hipLaunchKernelGGL(k13_topk, dim3(1024), dim3(256), 0, stream, emb, embT, rsqm, topk, x, part, mr, o);
    hipLaunchKernelGGL(k2_gemm_h, dim3(512), dim3(256), 0, stream, x, wt, mr, h, atti, attj, eai, eaj, ai, aj);
    hipLaunchKernelGGL(k5_attn,  dim3(8192), dim3(256), 0, stream, h, ai, aj, topk, gnnb, outg, x);
    hipLaunchKernelGGL(k5b_stats, dim3(256), dim3(256), 0, stream, outg, stats);
    hipLaunchKernelGGL(k6_stats2, dim3(512), dim3(256), 0, stream, outg, stats, g1, b1, emb, stats + 128, x);
    hipLaunchKernelGGL(k7_out,   dim3(512),  dim3(256), 0, stream, outg, stats, stats + 128,
                       g1, b1, g2, b2, emb, outw, outb, o, x);
}